// Round 5
// baseline (469.995 us; speedup 1.0000x reference)
//
#include <hip/hip_runtime.h>
#include <hip/hip_bf16.h>

// FastASTEncoder round 5: GEMM = BK=32 double-buffered counted-vmcnt pipeline at
// 24KB LDS (6 blocks/CU — round-4 regression was 48KB LDS halving occupancy),
// round-2-proven (row>>1)&3 XOR swizzle; vectorized LN; round-4 attn kept.
//
// Workspace (~92 MiB):
//   [0,32M)   p0/p1 fp32 partials [2][8192][512]  (overlaps qkvb bf16 [8192][1536])
//   [32,64M)  h1   bf16 [8192][2048]
//   [64,72M)  xb   bf16 [8192][512]
//   [72,80M)  cbuf bf16 [8192][512]
//   [80M+)    transposed bf16 weights

#define BB 16
#define NN 512
#define DMM 512
#define HH 8
#define DKK 64
#define RR 8
#define LL 2
#define DFFV 2048
#define PAR_HEADS 4
#define EPSV 1e-5f

typedef __bf16 bf16x8 __attribute__((ext_vector_type(8)));
typedef float f32x4 __attribute__((ext_vector_type(4)));
typedef unsigned short u16x8 __attribute__((ext_vector_type(8)));

__device__ __forceinline__ unsigned short f2bf(float f) {
    unsigned u = __float_as_uint(f);
    u += 0x7fff + ((u >> 16) & 1);   // RNE
    return (unsigned short)(u >> 16);
}
__device__ __forceinline__ float bf2f(unsigned short u) {
    return __uint_as_float(((unsigned)u) << 16);
}

// ---------------- fused transpose for the four [512][512] weight sets ----------------
__global__ __launch_bounds__(256) void transpose_qkvo_kernel(
    const float* __restrict__ Wq, const float* __restrict__ Wk,
    const float* __restrict__ Wv, const float* __restrict__ Wo,
    unsigned short* __restrict__ wqkvT, unsigned short* __restrict__ woT)
{
    __shared__ float tile[32][33];
    int layer = blockIdx.z >> 2, which = blockIdx.z & 3;
    const float* s = (which == 0 ? Wq : which == 1 ? Wk : which == 2 ? Wv : Wo)
                     + (size_t)layer * DMM * DMM;
    unsigned short* d = (which < 3)
        ? wqkvT + (size_t)layer * 1536 * DMM + (size_t)which * DMM * DMM
        : woT + (size_t)layer * DMM * DMM;
    int k0 = blockIdx.y * 32, n0 = blockIdx.x * 32;
    int tx = threadIdx.x & 31, ty = threadIdx.x >> 5;
#pragma unroll
    for (int i = 0; i < 4; ++i)
        tile[ty + i * 8][tx] = s[(size_t)(k0 + ty + i * 8) * DMM + (n0 + tx)];
    __syncthreads();
#pragma unroll
    for (int i = 0; i < 4; ++i)
        d[(size_t)(n0 + ty + i * 8) * DMM + (k0 + tx)] = f2bf(tile[tx][ty + i * 8]);
}

// generic transpose [z][K][N] fp32 -> bf16 [N][K] (for W1, W2)
__global__ __launch_bounds__(256) void transpose_w_kernel(
    const float* __restrict__ src, unsigned short* __restrict__ dst,
    int K, int N, size_t zStride)
{
    __shared__ float tile[32][33];
    const float* s = src + (size_t)blockIdx.z * K * N;
    unsigned short* d = dst + (size_t)blockIdx.z * zStride;
    int k0 = blockIdx.y * 32, n0 = blockIdx.x * 32;
    int tx = threadIdx.x & 31, ty = threadIdx.x >> 5;
#pragma unroll
    for (int i = 0; i < 4; ++i)
        tile[ty + i * 8][tx] = s[(size_t)(k0 + ty + i * 8) * N + (n0 + tx)];
    __syncthreads();
#pragma unroll
    for (int i = 0; i < 4; ++i)
        d[(size_t)(n0 + ty + i * 8) * K + (k0 + tx)] = f2bf(tile[tx][ty + i * 8]);
}

// ---------------- x init ----------------
__global__ __launch_bounds__(256) void convert_x_kernel(
    const float* __restrict__ src, float* __restrict__ x, unsigned short* __restrict__ xb, int n4)
{
    int i = blockIdx.x * blockDim.x + threadIdx.x;
    int stride = gridDim.x * blockDim.x;
    for (; i < n4; i += stride) {
        float4 f = ((const float4*)src)[i];
        ((float4*)x)[i] = f;
        ushort4 u;
        u.x = f2bf(f.x); u.y = f2bf(f.y); u.z = f2bf(f.z); u.w = f2bf(f.w);
        ((ushort4*)xb)[i] = u;
    }
}

// ---------------- bf16 GEMM: C[M][N] = A[M][K] @ Bt[N][K]^T ----------------
// Tile 128x64, BK=32, 4 waves, double-buffered LDS (24KB total -> 6 blocks/CU),
// counted vmcnt: per iter {stage next (3 loads/thread) -> vmcnt(3) -> barrier ->
// ds_read + 8 MFMA -> barrier}. LDS 4-slot XOR swizzle slot^((row>>1)&3)
// (round-2-proven conflict-free, applied both-sides per rule #21).
template<bool OUTBF, bool DORELU>
__global__ __launch_bounds__(256) void gemm_kernel(
    const unsigned short* __restrict__ A,   // [M][K] bf16
    const unsigned short* __restrict__ Bt,  // [N][K] bf16
    float* __restrict__ Cf,                 // fp32 out (if !OUTBF)
    unsigned short* __restrict__ Cb,        // bf16 out (if OUTBF)
    const float* __restrict__ bias,         // [N] or null
    int M, int N, int K, int kLen)
{
    constexpr int BM = 128, BN = 64, BK = 32;
    __shared__ __align__(16) unsigned short As[2][BM * BK];
    __shared__ __align__(16) unsigned short Bs[2][BN * BK];
    int tid = threadIdx.x, lane = tid & 63, w = tid >> 6;
    int wr = w >> 1, wc = w & 1;

    // XCD-bijective swizzle over (x,y); nwg % 8 == 0 for all our grids
    int gx = gridDim.x;
    int nwg = gx * gridDim.y;
    int flat = blockIdx.x + gx * blockIdx.y;
    int qq = nwg >> 3;
    int swz = (flat & 7) * qq + (flat >> 3);
    int bx = swz % gx, by = swz / gx;
    int mBase = by * BM, nBase = bx * BN;
    int kStart = blockIdx.z * kLen;

    const unsigned short* gA = A + (size_t)mBase * K;
    const unsigned short* gB = Bt + (size_t)nBase * K;

    f32x4 acc[4][2];
#pragma unroll
    for (int i = 0; i < 4; ++i)
#pragma unroll
        for (int j = 0; j < 2; ++j) acc[i][j] = (f32x4){0.f, 0.f, 0.f, 0.f};

    // stage one K-tile into buffer buf: A = 512 16B-units, B = 256 units
    auto stage = [&](int buf, int k0) {
#pragma unroll
        for (int it = 0; it < 2; ++it) {
            int i = it * 256 + tid;
            int row = i >> 2, slot = i & 3;
            int gcol = (slot ^ ((row >> 1) & 3)) * 8;
            __builtin_amdgcn_global_load_lds(
                (const __attribute__((address_space(1))) void*)(gA + (size_t)row * K + k0 + gcol),
                (__attribute__((address_space(3))) void*)(As[buf] + i * 8), 16, 0, 0);
        }
        {
            int i = tid;
            int row = i >> 2, slot = i & 3;
            int gcol = (slot ^ ((row >> 1) & 3)) * 8;
            __builtin_amdgcn_global_load_lds(
                (const __attribute__((address_space(1))) void*)(gB + (size_t)row * K + k0 + gcol),
                (__attribute__((address_space(3))) void*)(Bs[buf] + i * 8), 16, 0, 0);
        }
    };

    int nt = kLen / BK;
    stage(0, kStart);
    int cur = 0;
    for (int t = 0; t < nt; ++t) {
        if (t + 1 < nt) {
            stage(cur ^ 1, kStart + (t + 1) * BK);
            asm volatile("s_waitcnt vmcnt(3)" ::: "memory");   // cur's 3 done; next's 3 in flight
        } else {
            asm volatile("s_waitcnt vmcnt(0)" ::: "memory");
        }
        __builtin_amdgcn_s_barrier();

        int rsel = lane & 15, g0 = lane >> 4;
        bf16x8 a[4], b[2];
#pragma unroll
        for (int m = 0; m < 4; ++m) {
            int row = wr * 64 + m * 16 + rsel;
            int s = g0 ^ ((row >> 1) & 3);
            a[m] = *(const bf16x8*)((const char*)As[cur] + row * 64 + s * 16);
        }
#pragma unroll
        for (int n = 0; n < 2; ++n) {
            int row = wc * 32 + n * 16 + rsel;
            int s = g0 ^ ((row >> 1) & 3);
            b[n] = *(const bf16x8*)((const char*)Bs[cur] + row * 64 + s * 16);
        }
#pragma unroll
        for (int m = 0; m < 4; ++m)
#pragma unroll
            for (int n = 0; n < 2; ++n)
                acc[m][n] = __builtin_amdgcn_mfma_f32_16x16x32_bf16(a[m], b[n], acc[m][n], 0, 0, 0);
        __builtin_amdgcn_s_barrier();
        cur ^= 1;
    }

    // epilogue: C/D layout col=lane&15, row=(lane>>4)*4+j  [m89-verified]
    size_t zoff = (size_t)blockIdx.z * M * N;
    int rbase = (lane >> 4) * 4;
    int cloc = lane & 15;
#pragma unroll
    for (int m = 0; m < 4; ++m) {
#pragma unroll
        for (int n = 0; n < 2; ++n) {
            int col = nBase + wc * 32 + n * 16 + cloc;
            float bv = bias ? bias[col] : 0.0f;
#pragma unroll
            for (int j = 0; j < 4; ++j) {
                int row = mBase + wr * 64 + m * 16 + rbase + j;
                float val = acc[m][n][j] + bv;
                if (DORELU) val = fmaxf(val, 0.0f);
                if (OUTBF) Cb[zoff + (size_t)row * N + col] = f2bf(val);
                else       Cf[zoff + (size_t)row * N + col] = val;
            }
        }
    }
}

// ---------------- sparse relational attention (round-4 structure) ----------------
__global__ __launch_bounds__(256) void attn_kernel(
    const unsigned short* __restrict__ qkv,
    const int* __restrict__ par, const int* __restrict__ bro,
    const float* __restrict__ relq, const float* __restrict__ relk,
    const float* __restrict__ relv, unsigned short* __restrict__ cb)
{
    int f = blockIdx.x;
    int xcd = f & 7;
    int j = f >> 3;                 // 0..255
    int b = xcd + 8 * (j & 1);
    int rem = j >> 1;               // 0..127
    int h = rem >> 4;               // 0..7
    int n0 = (rem & 15) * 32;
    int w = threadIdx.x >> 6;
    int lane = threadIdx.x & 63;
    int nw = n0 + w * 8;

    float rq[RR], rk[RR], rv[RR];
#pragma unroll
    for (int r = 0; r < RR; ++r) {
        rq[r] = relq[(h * RR + r) * DKK + lane];
        rk[r] = relk[(h * RR + r) * DKK + lane];
        rv[r] = relv[(h * RR + r) * DKK + lane];
    }
    const int* edges = (h < PAR_HEADS) ? par : bro;
    int e_all = edges[(b * RR + (lane & 7)) * NN + nw + (lane >> 3)];

    const unsigned short* qrow = qkv + (size_t)b * NN * 1536 + h * DKK;

#pragma unroll
    for (int nl = 0; nl < 8; ++nl) {
        int n = nw + nl;
        float qd = bf2f(qrow[(size_t)n * 1536 + lane]);
        float t[RR];
        int e[RR];
#pragma unroll
        for (int r = 0; r < RR; ++r) {
            int er = __builtin_amdgcn_readlane(e_all, nl * 8 + r);   // SGPR base
            e[r] = er;
            float kd = bf2f(qkv[(size_t)(b * NN + er) * 1536 + DMM + h * DKK + lane]);
            t[r] = kd * (qd + rq[r]) + qd * rk[r];
        }
        {
            bool hb = lane & 4;
#pragma unroll
            for (int rr = 0; rr < 4; ++rr) {
                float send = hb ? t[rr] : t[rr + 4];
                float keep = hb ? t[rr + 4] : t[rr];
                t[rr] = keep + __shfl_xor(send, 4, 64);
            }
        }
        {
            bool hb = lane & 2;
#pragma unroll
            for (int rr = 0; rr < 2; ++rr) {
                float send = hb ? t[rr] : t[rr + 2];
                float keep = hb ? t[rr + 2] : t[rr];
                t[rr] = keep + __shfl_xor(send, 2, 64);
            }
        }
        {
            bool hb = lane & 1;
            float send = hb ? t[0] : t[1];
            float keep = hb ? t[1] : t[0];
            t[0] = keep + __shfl_xor(send, 1, 64);
        }
        float s = t[0];
        s += __shfl_xor(s, 8, 64);
        s += __shfl_xor(s, 16, 64);
        s += __shfl_xor(s, 32, 64);
        s *= 0.125f;
        float mx = s;
        mx = fmaxf(mx, __shfl_xor(mx, 1, 64));
        mx = fmaxf(mx, __shfl_xor(mx, 2, 64));
        mx = fmaxf(mx, __shfl_xor(mx, 4, 64));
        float ee = __expf(s - mx);
        float den = ee;
        den += __shfl_xor(den, 1, 64);
        den += __shfl_xor(den, 2, 64);
        den += __shfl_xor(den, 4, 64);
        float a = ee / den;
        float od = 0.f;
#pragma unroll
        for (int r = 0; r < RR; ++r) {
            float ar = __shfl(a, (lane & 56) | r, 64);
            float vd = bf2f(qkv[(size_t)(b * NN + e[r]) * 1536 + 2 * DMM + h * DKK + lane]);
            od = fmaf(ar, vd + rv[r], od);
        }
        cb[(size_t)(b * NN + n) * DMM + h * DKK + lane] = f2bf(od);
    }
}

// ---------------- residual(+partials+bias) + LayerNorm, vectorized ----------------
// one wave per row of 512; lane handles 8 contiguous cols (2 x float4)
__global__ __launch_bounds__(256) void ln_kernel(
    const float* __restrict__ xin, const float* __restrict__ add0,
    const float* __restrict__ add1, const float* __restrict__ bias,
    float* __restrict__ xout, unsigned short* __restrict__ xbout,
    const float* __restrict__ g, const float* __restrict__ bb)
{
    int row = blockIdx.x * 4 + (threadIdx.x >> 6);
    int lane = threadIdx.x & 63;
    int c0 = lane * 8;
    const float* xr = xin + (size_t)row * DMM + c0;
    float vals[8];
    {
        float4 v0 = *(const float4*)xr;
        float4 v1 = *(const float4*)(xr + 4);
        vals[0] = v0.x; vals[1] = v0.y; vals[2] = v0.z; vals[3] = v0.w;
        vals[4] = v1.x; vals[5] = v1.y; vals[6] = v1.z; vals[7] = v1.w;
    }
    if (add0) {
        const float* ar = add0 + (size_t)row * DMM + c0;
        float4 v0 = *(const float4*)ar, v1 = *(const float4*)(ar + 4);
        vals[0] += v0.x; vals[1] += v0.y; vals[2] += v0.z; vals[3] += v0.w;
        vals[4] += v1.x; vals[5] += v1.y; vals[6] += v1.z; vals[7] += v1.w;
    }
    if (add1) {
        const float* ar = add1 + (size_t)row * DMM + c0;
        float4 v0 = *(const float4*)ar, v1 = *(const float4*)(ar + 4);
        vals[0] += v0.x; vals[1] += v0.y; vals[2] += v0.z; vals[3] += v0.w;
        vals[4] += v1.x; vals[5] += v1.y; vals[6] += v1.z; vals[7] += v1.w;
    }
    if (bias) {
        float4 v0 = *(const float4*)(bias + c0), v1 = *(const float4*)(bias + c0 + 4);
        vals[0] += v0.x; vals[1] += v0.y; vals[2] += v0.z; vals[3] += v0.w;
        vals[4] += v1.x; vals[5] += v1.y; vals[6] += v1.z; vals[7] += v1.w;
    }
    float s = 0.f;
#pragma unroll
    for (int j = 0; j < 8; ++j) s += vals[j];
#pragma unroll
    for (int off = 32; off > 0; off >>= 1) s += __shfl_xor(s, off, 64);
    float mean = s * (1.0f / DMM);
    float s2 = 0.f;
#pragma unroll
    for (int j = 0; j < 8; ++j) { float d = vals[j] - mean; s2 += d * d; }
#pragma unroll
    for (int off = 32; off > 0; off >>= 1) s2 += __shfl_xor(s2, off, 64);
    float inv = rsqrtf(s2 * (1.0f / DMM) + EPSV);

    float4 gv0 = *(const float4*)(g + c0), gv1 = *(const float4*)(g + c0 + 4);
    float4 bv0 = *(const float4*)(bb + c0), bv1 = *(const float4*)(bb + c0 + 4);
    float y[8];
    y[0] = (vals[0] - mean) * inv * gv0.x + bv0.x;
    y[1] = (vals[1] - mean) * inv * gv0.y + bv0.y;
    y[2] = (vals[2] - mean) * inv * gv0.z + bv0.z;
    y[3] = (vals[3] - mean) * inv * gv0.w + bv0.w;
    y[4] = (vals[4] - mean) * inv * gv1.x + bv1.x;
    y[5] = (vals[5] - mean) * inv * gv1.y + bv1.y;
    y[6] = (vals[6] - mean) * inv * gv1.z + bv1.z;
    y[7] = (vals[7] - mean) * inv * gv1.w + bv1.w;

    float* xo = xout + (size_t)row * DMM + c0;
    *(float4*)xo = make_float4(y[0], y[1], y[2], y[3]);
    *(float4*)(xo + 4) = make_float4(y[4], y[5], y[6], y[7]);
    if (xbout) {
        u16x8 u;
#pragma unroll
        for (int j = 0; j < 8; ++j) u[j] = f2bf(y[j]);
        *(u16x8*)(xbout + (size_t)row * DMM + c0) = u;
    }
}

extern "C" void kernel_launch(void* const* d_in, const int* in_sizes, int n_in,
                              void* d_out, int out_size, void* d_ws, size_t ws_size,
                              hipStream_t stream)
{
    const float* src_emb = (const float*)d_in[0];
    const int*   par     = (const int*)d_in[1];
    const int*   bro     = (const int*)d_in[2];
    const float* rel_q   = (const float*)d_in[3];
    const float* rel_k   = (const float*)d_in[4];
    const float* rel_v   = (const float*)d_in[5];
    const float* Wq      = (const float*)d_in[6];
    const float* Wk      = (const float*)d_in[7];
    const float* Wv      = (const float*)d_in[8];
    const float* Wo      = (const float*)d_in[9];
    const float* ln1_g   = (const float*)d_in[10];
    const float* ln1_b   = (const float*)d_in[11];
    const float* W1      = (const float*)d_in[12];
    const float* b1      = (const float*)d_in[13];
    const float* W2      = (const float*)d_in[14];
    const float* b2      = (const float*)d_in[15];
    const float* ln2_g   = (const float*)d_in[16];
    const float* ln2_b   = (const float*)d_in[17];
    const float* normf_g = (const float*)d_in[18];
    const float* normf_b = (const float*)d_in[19];

    const size_t MB = 1024 * 1024;
    const int M = BB * NN;  // 8192
    char* ws = (char*)d_ws;
    float*          p    = (float*)(ws + 0 * MB);
    unsigned short* qkvb = (unsigned short*)(ws + 0 * MB);    // overlaps p (disjoint lifetime)
    unsigned short* h1   = (unsigned short*)(ws + 32 * MB);
    unsigned short* xb   = (unsigned short*)(ws + 64 * MB);
    unsigned short* cbuf = (unsigned short*)(ws + 72 * MB);
    unsigned short* wqkvT = (unsigned short*)(ws + 80 * MB);
    unsigned short* woT  = wqkvT + (size_t)LL * 1536 * DMM;
    unsigned short* w1T  = woT + (size_t)LL * DMM * DMM;
    unsigned short* w2T  = w1T + (size_t)LL * DMM * DFFV;
    float* p0 = p;
    float* p1 = p + (size_t)M * DMM;
    float* x = (float*)d_out;

    transpose_qkvo_kernel<<<dim3(16, 16, LL * 4), 256, 0, stream>>>(
        Wq, Wk, Wv, Wo, wqkvT, woT);
    transpose_w_kernel<<<dim3(DFFV / 32, DMM / 32, LL), 256, 0, stream>>>(
        W1, w1T, DMM, DFFV, (size_t)DMM * DFFV);
    transpose_w_kernel<<<dim3(DMM / 32, DFFV / 32, LL), 256, 0, stream>>>(
        W2, w2T, DFFV, DMM, (size_t)DMM * DFFV);

    convert_x_kernel<<<2048, 256, 0, stream>>>(src_emb, x, xb, M * DMM / 4);

    for (int l = 0; l < LL; ++l) {
        const unsigned short* wqkv_l = wqkvT + (size_t)l * 1536 * DMM;
        const unsigned short* wo_l = woT + (size_t)l * DMM * DMM;
        const unsigned short* w1_l = w1T + (size_t)l * DMM * DFFV;
        const unsigned short* w2_l = w2T + (size_t)l * DFFV * DMM;

        // fused QKV: [8192,512]@[512,1536] -> bf16 qkvb; grid 1536 = 6 blocks/CU
        gemm_kernel<true, false><<<dim3(1536 / 64, M / 128, 1), 256, 0, stream>>>(
            xb, wqkv_l, nullptr, qkvb, nullptr, M, 1536, DMM, DMM);

        attn_kernel<<<2048, 256, 0, stream>>>(qkvb, par, bro, rel_q, rel_k, rel_v, cbuf);

        // Wo: split-K=2; partials summed in ln1
        gemm_kernel<false, false><<<dim3(512 / 64, M / 128, 2), 256, 0, stream>>>(
            cbuf, wo_l, p, nullptr, nullptr, M, DMM, DMM, DMM / 2);
        ln_kernel<<<M / 4, 256, 0, stream>>>(x, p0, p1, nullptr, x, xb,
                                             ln1_g + l * DMM, ln1_b + l * DMM);

        // W1: bias+relu, bf16 out; grid 2048 = 8 blocks/CU
        gemm_kernel<true, true><<<dim3(DFFV / 64, M / 128, 1), 256, 0, stream>>>(
            xb, w1_l, nullptr, h1, b1 + l * DFFV, M, DFFV, DMM, DMM);
        // W2: split-K=2 (K=1024 each); b2 added in ln2
        gemm_kernel<false, false><<<dim3(512 / 64, M / 128, 2), 256, 0, stream>>>(
            h1, w2_l, p, nullptr, nullptr, M, DMM, DFFV, DFFV / 2);
        ln_kernel<<<M / 4, 256, 0, stream>>>(x, p0, p1, b2 + l * DMM, x, xb,
                                             ln2_g + l * DMM, ln2_b + l * DMM);
    }

    ln_kernel<<<M / 4, 256, 0, stream>>>(x, nullptr, nullptr, nullptr, x, nullptr,
                                         normf_g, normf_b);
}

// Round 7
// 457.208 us; speedup vs baseline: 1.0280x; 1.0280x over previous
//
#include <hip/hip_runtime.h>
#include <hip/hip_bf16.h>

// FastASTEncoder round 6 (resubmit — r6 bench timed out): GEMM reverted verbatim
// to round-3 structure (BK=64 single-buffer, 24KB LDS, 6 blocks/CU — both
// pipelining attempts r4/r5 lost to it, consistent with m99/m131-m141: implicit
// wave overlap suffices at 24 w/CU). Keeps round-4 attn (<40us) and round-5
// vectorized LN.
//
// Workspace (~92 MiB):
//   [0,32M)   p0/p1 fp32 partials [2][8192][512]  (overlaps qkvb bf16 [8192][1536])
//   [32,64M)  h1   bf16 [8192][2048]
//   [64,72M)  xb   bf16 [8192][512]
//   [72,80M)  cbuf bf16 [8192][512]
//   [80M+)    transposed bf16 weights

#define BB 16
#define NN 512
#define DMM 512
#define HH 8
#define DKK 64
#define RR 8
#define LL 2
#define DFFV 2048
#define PAR_HEADS 4
#define EPSV 1e-5f

typedef __bf16 bf16x8 __attribute__((ext_vector_type(8)));
typedef float f32x4 __attribute__((ext_vector_type(4)));
typedef unsigned short u16x8 __attribute__((ext_vector_type(8)));

__device__ __forceinline__ unsigned short f2bf(float f) {
    unsigned u = __float_as_uint(f);
    u += 0x7fff + ((u >> 16) & 1);   // RNE
    return (unsigned short)(u >> 16);
}
__device__ __forceinline__ float bf2f(unsigned short u) {
    return __uint_as_float(((unsigned)u) << 16);
}

// ---------------- fused transpose for the four [512][512] weight sets ----------------
__global__ __launch_bounds__(256) void transpose_qkvo_kernel(
    const float* __restrict__ Wq, const float* __restrict__ Wk,
    const float* __restrict__ Wv, const float* __restrict__ Wo,
    unsigned short* __restrict__ wqkvT, unsigned short* __restrict__ woT)
{
    __shared__ float tile[32][33];
    int layer = blockIdx.z >> 2, which = blockIdx.z & 3;
    const float* s = (which == 0 ? Wq : which == 1 ? Wk : which == 2 ? Wv : Wo)
                     + (size_t)layer * DMM * DMM;
    unsigned short* d = (which < 3)
        ? wqkvT + (size_t)layer * 1536 * DMM + (size_t)which * DMM * DMM
        : woT + (size_t)layer * DMM * DMM;
    int k0 = blockIdx.y * 32, n0 = blockIdx.x * 32;
    int tx = threadIdx.x & 31, ty = threadIdx.x >> 5;
#pragma unroll
    for (int i = 0; i < 4; ++i)
        tile[ty + i * 8][tx] = s[(size_t)(k0 + ty + i * 8) * DMM + (n0 + tx)];
    __syncthreads();
#pragma unroll
    for (int i = 0; i < 4; ++i)
        d[(size_t)(n0 + ty + i * 8) * DMM + (k0 + tx)] = f2bf(tile[tx][ty + i * 8]);
}

// generic transpose [z][K][N] fp32 -> bf16 [N][K] (for W1, W2)
__global__ __launch_bounds__(256) void transpose_w_kernel(
    const float* __restrict__ src, unsigned short* __restrict__ dst,
    int K, int N, size_t zStride)
{
    __shared__ float tile[32][33];
    const float* s = src + (size_t)blockIdx.z * K * N;
    unsigned short* d = dst + (size_t)blockIdx.z * zStride;
    int k0 = blockIdx.y * 32, n0 = blockIdx.x * 32;
    int tx = threadIdx.x & 31, ty = threadIdx.x >> 5;
#pragma unroll
    for (int i = 0; i < 4; ++i)
        tile[ty + i * 8][tx] = s[(size_t)(k0 + ty + i * 8) * N + (n0 + tx)];
    __syncthreads();
#pragma unroll
    for (int i = 0; i < 4; ++i)
        d[(size_t)(n0 + ty + i * 8) * K + (k0 + tx)] = f2bf(tile[tx][ty + i * 8]);
}

// ---------------- x init ----------------
__global__ __launch_bounds__(256) void convert_x_kernel(
    const float* __restrict__ src, float* __restrict__ x, unsigned short* __restrict__ xb, int n4)
{
    int i = blockIdx.x * blockDim.x + threadIdx.x;
    int stride = gridDim.x * blockDim.x;
    for (; i < n4; i += stride) {
        float4 f = ((const float4*)src)[i];
        ((float4*)x)[i] = f;
        ushort4 u;
        u.x = f2bf(f.x); u.y = f2bf(f.y); u.z = f2bf(f.z); u.w = f2bf(f.w);
        ((ushort4*)xb)[i] = u;
    }
}

// ---------------- bf16 GEMM: C[M][N] = A[M][K] @ Bt[N][K]^T (round-3 structure) ----
// Tile 128x64, BK=64, 4 waves (2x2), wave tile 64x32, 16 MFMA/wave/K-step.
// LDS row = 128B = 8 x 16B slots; LDS(row,slot) = global(row, slot^(row&7))
// (both-sides XOR swizzle, rule #21; 0 conflicts measured). Split-K via blockIdx.z.
template<bool OUTBF, bool DORELU>
__global__ __launch_bounds__(256) void gemm_kernel(
    const unsigned short* __restrict__ A,   // [M][K] bf16
    const unsigned short* __restrict__ Bt,  // [N][K] bf16
    float* __restrict__ Cf,                 // fp32 out (if !OUTBF)
    unsigned short* __restrict__ Cb,        // bf16 out (if OUTBF)
    const float* __restrict__ bias,         // [N] or null
    int M, int N, int K, int kLen)
{
    constexpr int BM = 128, BN = 64, BK = 64;
    __shared__ __align__(16) unsigned short As[BM * BK];
    __shared__ __align__(16) unsigned short Bs[BN * BK];
    int tid = threadIdx.x, lane = tid & 63, w = tid >> 6;
    int wr = w >> 1, wc = w & 1;

    // XCD-bijective swizzle over (x,y); nwg % 8 == 0 for all our grids
    int gx = gridDim.x;
    int nwg = gx * gridDim.y;
    int flat = blockIdx.x + gx * blockIdx.y;
    int qq = nwg >> 3;
    int swz = (flat & 7) * qq + (flat >> 3);
    int bx = swz % gx, by = swz / gx;
    int mBase = by * BM, nBase = bx * BN;
    int kStart = blockIdx.z * kLen;

    f32x4 acc[4][2];
#pragma unroll
    for (int i = 0; i < 4; ++i)
#pragma unroll
        for (int j = 0; j < 2; ++j) acc[i][j] = (f32x4){0.f, 0.f, 0.f, 0.f};

    for (int k0 = kStart; k0 < kStart + kLen; k0 += BK) {
        // stage A: 1024 16B units (row=i>>3, slot=i&7), source column pre-XOR-swizzled
#pragma unroll
        for (int it = 0; it < 4; ++it) {
            int i = it * 256 + tid;
            int row = i >> 3, slot = i & 7;
            int gcol = (slot ^ (row & 7)) * 8;
            const unsigned short* ga = A + (size_t)(mBase + row) * K + k0 + gcol;
            __builtin_amdgcn_global_load_lds(
                (const __attribute__((address_space(1))) void*)ga,
                (__attribute__((address_space(3))) void*)(As + i * 8), 16, 0, 0);
        }
#pragma unroll
        for (int it = 0; it < 2; ++it) {
            int i = it * 256 + tid;
            int row = i >> 3, slot = i & 7;
            int gcol = (slot ^ (row & 7)) * 8;
            const unsigned short* gb = Bt + (size_t)(nBase + row) * K + k0 + gcol;
            __builtin_amdgcn_global_load_lds(
                (const __attribute__((address_space(1))) void*)gb,
                (__attribute__((address_space(3))) void*)(Bs + i * 8), 16, 0, 0);
        }
        __syncthreads();

        int rsel = lane & 15, g0 = lane >> 4;
        bf16x8 a[4][2], b[2][2];
#pragma unroll
        for (int m = 0; m < 4; ++m) {
            int row = wr * 64 + m * 16 + rsel;
#pragma unroll
            for (int ks = 0; ks < 2; ++ks) {
                int s = (g0 + ks * 4) ^ (row & 7);
                a[m][ks] = *(const bf16x8*)((const char*)As + row * 128 + s * 16);
            }
        }
#pragma unroll
        for (int n = 0; n < 2; ++n) {
            int row = wc * 32 + n * 16 + rsel;
#pragma unroll
            for (int ks = 0; ks < 2; ++ks) {
                int s = (g0 + ks * 4) ^ (row & 7);
                b[n][ks] = *(const bf16x8*)((const char*)Bs + row * 128 + s * 16);
            }
        }
#pragma unroll
        for (int m = 0; m < 4; ++m)
#pragma unroll
            for (int n = 0; n < 2; ++n)
#pragma unroll
                for (int ks = 0; ks < 2; ++ks)
                    acc[m][n] = __builtin_amdgcn_mfma_f32_16x16x32_bf16(a[m][ks], b[n][ks], acc[m][n], 0, 0, 0);
        __syncthreads();
    }

    // epilogue: C/D layout col=lane&15, row=(lane>>4)*4+j  [m89-verified]
    size_t zoff = (size_t)blockIdx.z * M * N;
    int rbase = (lane >> 4) * 4;
    int cloc = lane & 15;
#pragma unroll
    for (int m = 0; m < 4; ++m) {
#pragma unroll
        for (int n = 0; n < 2; ++n) {
            int col = nBase + wc * 32 + n * 16 + cloc;
            float bv = bias ? bias[col] : 0.0f;
#pragma unroll
            for (int j = 0; j < 4; ++j) {
                int row = mBase + wr * 64 + m * 16 + rbase + j;
                float val = acc[m][n][j] + bv;
                if (DORELU) val = fmaxf(val, 0.0f);
                if (OUTBF) Cb[zoff + (size_t)row * N + col] = f2bf(val);
                else       Cf[zoff + (size_t)row * N + col] = val;
            }
        }
    }
}

// ---------------- sparse relational attention (round-4 structure) ----------------
__global__ __launch_bounds__(256) void attn_kernel(
    const unsigned short* __restrict__ qkv,
    const int* __restrict__ par, const int* __restrict__ bro,
    const float* __restrict__ relq, const float* __restrict__ relk,
    const float* __restrict__ relv, unsigned short* __restrict__ cb)
{
    int f = blockIdx.x;
    int xcd = f & 7;
    int j = f >> 3;                 // 0..255
    int b = xcd + 8 * (j & 1);
    int rem = j >> 1;               // 0..127
    int h = rem >> 4;               // 0..7
    int n0 = (rem & 15) * 32;
    int w = threadIdx.x >> 6;
    int lane = threadIdx.x & 63;
    int nw = n0 + w * 8;

    float rq[RR], rk[RR], rv[RR];
#pragma unroll
    for (int r = 0; r < RR; ++r) {
        rq[r] = relq[(h * RR + r) * DKK + lane];
        rk[r] = relk[(h * RR + r) * DKK + lane];
        rv[r] = relv[(h * RR + r) * DKK + lane];
    }
    const int* edges = (h < PAR_HEADS) ? par : bro;
    int e_all = edges[(b * RR + (lane & 7)) * NN + nw + (lane >> 3)];

    const unsigned short* qrow = qkv + (size_t)b * NN * 1536 + h * DKK;

#pragma unroll
    for (int nl = 0; nl < 8; ++nl) {
        int n = nw + nl;
        float qd = bf2f(qrow[(size_t)n * 1536 + lane]);
        float t[RR];
        int e[RR];
#pragma unroll
        for (int r = 0; r < RR; ++r) {
            int er = __builtin_amdgcn_readlane(e_all, nl * 8 + r);   // SGPR base
            e[r] = er;
            float kd = bf2f(qkv[(size_t)(b * NN + er) * 1536 + DMM + h * DKK + lane]);
            t[r] = kd * (qd + rq[r]) + qd * rk[r];
        }
        {
            bool hb = lane & 4;
#pragma unroll
            for (int rr = 0; rr < 4; ++rr) {
                float send = hb ? t[rr] : t[rr + 4];
                float keep = hb ? t[rr + 4] : t[rr];
                t[rr] = keep + __shfl_xor(send, 4, 64);
            }
        }
        {
            bool hb = lane & 2;
#pragma unroll
            for (int rr = 0; rr < 2; ++rr) {
                float send = hb ? t[rr] : t[rr + 2];
                float keep = hb ? t[rr + 2] : t[rr];
                t[rr] = keep + __shfl_xor(send, 2, 64);
            }
        }
        {
            bool hb = lane & 1;
            float send = hb ? t[0] : t[1];
            float keep = hb ? t[1] : t[0];
            t[0] = keep + __shfl_xor(send, 1, 64);
        }
        float s = t[0];
        s += __shfl_xor(s, 8, 64);
        s += __shfl_xor(s, 16, 64);
        s += __shfl_xor(s, 32, 64);
        s *= 0.125f;
        float mx = s;
        mx = fmaxf(mx, __shfl_xor(mx, 1, 64));
        mx = fmaxf(mx, __shfl_xor(mx, 2, 64));
        mx = fmaxf(mx, __shfl_xor(mx, 4, 64));
        float ee = __expf(s - mx);
        float den = ee;
        den += __shfl_xor(den, 1, 64);
        den += __shfl_xor(den, 2, 64);
        den += __shfl_xor(den, 4, 64);
        float a = ee / den;
        float od = 0.f;
#pragma unroll
        for (int r = 0; r < RR; ++r) {
            float ar = __shfl(a, (lane & 56) | r, 64);
            float vd = bf2f(qkv[(size_t)(b * NN + e[r]) * 1536 + 2 * DMM + h * DKK + lane]);
            od = fmaf(ar, vd + rv[r], od);
        }
        cb[(size_t)(b * NN + n) * DMM + h * DKK + lane] = f2bf(od);
    }
}

// ---------------- residual(+partials+bias) + LayerNorm, vectorized ----------------
__global__ __launch_bounds__(256) void ln_kernel(
    const float* __restrict__ xin, const float* __restrict__ add0,
    const float* __restrict__ add1, const float* __restrict__ bias,
    float* __restrict__ xout, unsigned short* __restrict__ xbout,
    const float* __restrict__ g, const float* __restrict__ bb)
{
    int row = blockIdx.x * 4 + (threadIdx.x >> 6);
    int lane = threadIdx.x & 63;
    int c0 = lane * 8;
    const float* xr = xin + (size_t)row * DMM + c0;
    float vals[8];
    {
        float4 v0 = *(const float4*)xr;
        float4 v1 = *(const float4*)(xr + 4);
        vals[0] = v0.x; vals[1] = v0.y; vals[2] = v0.z; vals[3] = v0.w;
        vals[4] = v1.x; vals[5] = v1.y; vals[6] = v1.z; vals[7] = v1.w;
    }
    if (add0) {
        const float* ar = add0 + (size_t)row * DMM + c0;
        float4 v0 = *(const float4*)ar, v1 = *(const float4*)(ar + 4);
        vals[0] += v0.x; vals[1] += v0.y; vals[2] += v0.z; vals[3] += v0.w;
        vals[4] += v1.x; vals[5] += v1.y; vals[6] += v1.z; vals[7] += v1.w;
    }
    if (add1) {
        const float* ar = add1 + (size_t)row * DMM + c0;
        float4 v0 = *(const float4*)ar, v1 = *(const float4*)(ar + 4);
        vals[0] += v0.x; vals[1] += v0.y; vals[2] += v0.z; vals[3] += v0.w;
        vals[4] += v1.x; vals[5] += v1.y; vals[6] += v1.z; vals[7] += v1.w;
    }
    if (bias) {
        float4 v0 = *(const float4*)(bias + c0), v1 = *(const float4*)(bias + c0 + 4);
        vals[0] += v0.x; vals[1] += v0.y; vals[2] += v0.z; vals[3] += v0.w;
        vals[4] += v1.x; vals[5] += v1.y; vals[6] += v1.z; vals[7] += v1.w;
    }
    float s = 0.f;
#pragma unroll
    for (int j = 0; j < 8; ++j) s += vals[j];
#pragma unroll
    for (int off = 32; off > 0; off >>= 1) s += __shfl_xor(s, off, 64);
    float mean = s * (1.0f / DMM);
    float s2 = 0.f;
#pragma unroll
    for (int j = 0; j < 8; ++j) { float d = vals[j] - mean; s2 += d * d; }
#pragma unroll
    for (int off = 32; off > 0; off >>= 1) s2 += __shfl_xor(s2, off, 64);
    float inv = rsqrtf(s2 * (1.0f / DMM) + EPSV);

    float4 gv0 = *(const float4*)(g + c0), gv1 = *(const float4*)(g + c0 + 4);
    float4 bv0 = *(const float4*)(bb + c0), bv1 = *(const float4*)(bb + c0 + 4);
    float y[8];
    y[0] = (vals[0] - mean) * inv * gv0.x + bv0.x;
    y[1] = (vals[1] - mean) * inv * gv0.y + bv0.y;
    y[2] = (vals[2] - mean) * inv * gv0.z + bv0.z;
    y[3] = (vals[3] - mean) * inv * gv0.w + bv0.w;
    y[4] = (vals[4] - mean) * inv * gv1.x + bv1.x;
    y[5] = (vals[5] - mean) * inv * gv1.y + bv1.y;
    y[6] = (vals[6] - mean) * inv * gv1.z + bv1.z;
    y[7] = (vals[7] - mean) * inv * gv1.w + bv1.w;

    float* xo = xout + (size_t)row * DMM + c0;
    *(float4*)xo = make_float4(y[0], y[1], y[2], y[3]);
    *(float4*)(xo + 4) = make_float4(y[4], y[5], y[6], y[7]);
    if (xbout) {
        u16x8 u;
#pragma unroll
        for (int j = 0; j < 8; ++j) u[j] = f2bf(y[j]);
        *(u16x8*)(xbout + (size_t)row * DMM + c0) = u;
    }
}

extern "C" void kernel_launch(void* const* d_in, const int* in_sizes, int n_in,
                              void* d_out, int out_size, void* d_ws, size_t ws_size,
                              hipStream_t stream)
{
    const float* src_emb = (const float*)d_in[0];
    const int*   par     = (const int*)d_in[1];
    const int*   bro     = (const int*)d_in[2];
    const float* rel_q   = (const float*)d_in[3];
    const float* rel_k   = (const float*)d_in[4];
    const float* rel_v   = (const float*)d_in[5];
    const float* Wq      = (const float*)d_in[6];
    const float* Wk      = (const float*)d_in[7];
    const float* Wv      = (const float*)d_in[8];
    const float* Wo      = (const float*)d_in[9];
    const float* ln1_g   = (const float*)d_in[10];
    const float* ln1_b   = (const float*)d_in[11];
    const float* W1      = (const float*)d_in[12];
    const float* b1      = (const float*)d_in[13];
    const float* W2      = (const float*)d_in[14];
    const float* b2      = (const float*)d_in[15];
    const float* ln2_g   = (const float*)d_in[16];
    const float* ln2_b   = (const float*)d_in[17];
    const float* normf_g = (const float*)d_in[18];
    const float* normf_b = (const float*)d_in[19];

    const size_t MB = 1024 * 1024;
    const int M = BB * NN;  // 8192
    char* ws = (char*)d_ws;
    float*          p    = (float*)(ws + 0 * MB);
    unsigned short* qkvb = (unsigned short*)(ws + 0 * MB);    // overlaps p (disjoint lifetime)
    unsigned short* h1   = (unsigned short*)(ws + 32 * MB);
    unsigned short* xb   = (unsigned short*)(ws + 64 * MB);
    unsigned short* cbuf = (unsigned short*)(ws + 72 * MB);
    unsigned short* wqkvT = (unsigned short*)(ws + 80 * MB);
    unsigned short* woT  = wqkvT + (size_t)LL * 1536 * DMM;
    unsigned short* w1T  = woT + (size_t)LL * DMM * DMM;
    unsigned short* w2T  = w1T + (size_t)LL * DMM * DFFV;
    float* p0 = p;
    float* p1 = p + (size_t)M * DMM;
    float* x = (float*)d_out;

    transpose_qkvo_kernel<<<dim3(16, 16, LL * 4), 256, 0, stream>>>(
        Wq, Wk, Wv, Wo, wqkvT, woT);
    transpose_w_kernel<<<dim3(DFFV / 32, DMM / 32, LL), 256, 0, stream>>>(
        W1, w1T, DMM, DFFV, (size_t)DMM * DFFV);
    transpose_w_kernel<<<dim3(DMM / 32, DFFV / 32, LL), 256, 0, stream>>>(
        W2, w2T, DFFV, DMM, (size_t)DMM * DFFV);

    convert_x_kernel<<<2048, 256, 0, stream>>>(src_emb, x, xb, M * DMM / 4);

    for (int l = 0; l < LL; ++l) {
        const unsigned short* wqkv_l = wqkvT + (size_t)l * 1536 * DMM;
        const unsigned short* wo_l = woT + (size_t)l * DMM * DMM;
        const unsigned short* w1_l = w1T + (size_t)l * DMM * DFFV;
        const unsigned short* w2_l = w2T + (size_t)l * DFFV * DMM;

        // fused QKV: [8192,512]@[512,1536] -> bf16 qkvb; grid 1536 = 6 blocks/CU
        gemm_kernel<true, false><<<dim3(1536 / 64, M / 128, 1), 256, 0, stream>>>(
            xb, wqkv_l, nullptr, qkvb, nullptr, M, 1536, DMM, DMM);

        attn_kernel<<<2048, 256, 0, stream>>>(qkvb, par, bro, rel_q, rel_k, rel_v, cbuf);

        // Wo: split-K=2; partials summed in ln1
        gemm_kernel<false, false><<<dim3(512 / 64, M / 128, 2), 256, 0, stream>>>(
            cbuf, wo_l, p, nullptr, nullptr, M, DMM, DMM, DMM / 2);
        ln_kernel<<<M / 4, 256, 0, stream>>>(x, p0, p1, nullptr, x, xb,
                                             ln1_g + l * DMM, ln1_b + l * DMM);

        // W1: bias+relu, bf16 out; grid 2048 = 8 blocks/CU
        gemm_kernel<true, true><<<dim3(DFFV / 64, M / 128, 1), 256, 0, stream>>>(
            xb, w1_l, nullptr, h1, b1 + l * DFFV, M, DFFV, DMM, DMM);
        // W2: split-K=2 (K=1024 each); b2 added in ln2
        gemm_kernel<false, false><<<dim3(512 / 64, M / 128, 2), 256, 0, stream>>>(
            h1, w2_l, p, nullptr, nullptr, M, DMM, DFFV, DFFV / 2);
        ln_kernel<<<M / 4, 256, 0, stream>>>(x, p0, p1, b2 + l * DMM, x, xb,
                                             ln2_g + l * DMM, ln2_b + l * DMM);
    }

    ln_kernel<<<M / 4, 256, 0, stream>>>(x, nullptr, nullptr, nullptr, x, nullptr,
                                         normf_g, normf_b);
}

// Round 10
// 438.020 us; speedup vs baseline: 1.0730x; 1.0438x over previous
//
#include <hip/hip_runtime.h>
#include <hip/hip_bf16.h>

// FastASTEncoder round 8 (resubmit x3 — acquisition timeouts): (1) 128x128 tiles
// (acc 4x4, BK=64) for QKV/W1 — same proven r3 single-buffer structure, better
// MFMA:overhead ratio; Wo/W2 keep 128x64 split-K=2. (2) bf16 residual stream:
// no fp32 x until the final LN (saves ~110MB traffic). attn = r4 structure.
//
// Workspace (~92 MiB):
//   [0,32M)   p0/p1 fp32 partials [2][8192][512]  (overlaps qkvb bf16 [8192][1536])
//   [32,64M)  h1   bf16 [8192][2048]
//   [64,72M)  xb   bf16 [8192][512]  (residual stream, bf16)
//   [72,80M)  cbuf bf16 [8192][512]
//   [80M+)    transposed bf16 weights

#define BB 16
#define NN 512
#define DMM 512
#define HH 8
#define DKK 64
#define RR 8
#define LL 2
#define DFFV 2048
#define PAR_HEADS 4
#define EPSV 1e-5f

typedef __bf16 bf16x8 __attribute__((ext_vector_type(8)));
typedef float f32x4 __attribute__((ext_vector_type(4)));
typedef unsigned short u16x8 __attribute__((ext_vector_type(8)));

__device__ __forceinline__ unsigned short f2bf(float f) {
    unsigned u = __float_as_uint(f);
    u += 0x7fff + ((u >> 16) & 1);   // RNE
    return (unsigned short)(u >> 16);
}
__device__ __forceinline__ float bf2f(unsigned short u) {
    return __uint_as_float(((unsigned)u) << 16);
}

// ---------------- fused transpose for the four [512][512] weight sets ----------------
__global__ __launch_bounds__(256) void transpose_qkvo_kernel(
    const float* __restrict__ Wq, const float* __restrict__ Wk,
    const float* __restrict__ Wv, const float* __restrict__ Wo,
    unsigned short* __restrict__ wqkvT, unsigned short* __restrict__ woT)
{
    __shared__ float tile[32][33];
    int layer = blockIdx.z >> 2, which = blockIdx.z & 3;
    const float* s = (which == 0 ? Wq : which == 1 ? Wk : which == 2 ? Wv : Wo)
                     + (size_t)layer * DMM * DMM;
    unsigned short* d = (which < 3)
        ? wqkvT + (size_t)layer * 1536 * DMM + (size_t)which * DMM * DMM
        : woT + (size_t)layer * DMM * DMM;
    int k0 = blockIdx.y * 32, n0 = blockIdx.x * 32;
    int tx = threadIdx.x & 31, ty = threadIdx.x >> 5;
#pragma unroll
    for (int i = 0; i < 4; ++i)
        tile[ty + i * 8][tx] = s[(size_t)(k0 + ty + i * 8) * DMM + (n0 + tx)];
    __syncthreads();
#pragma unroll
    for (int i = 0; i < 4; ++i)
        d[(size_t)(n0 + ty + i * 8) * DMM + (k0 + tx)] = f2bf(tile[tx][ty + i * 8]);
}

// generic transpose [z][K][N] fp32 -> bf16 [N][K] (for W1, W2)
__global__ __launch_bounds__(256) void transpose_w_kernel(
    const float* __restrict__ src, unsigned short* __restrict__ dst,
    int K, int N, size_t zStride)
{
    __shared__ float tile[32][33];
    const float* s = src + (size_t)blockIdx.z * K * N;
    unsigned short* d = dst + (size_t)blockIdx.z * zStride;
    int k0 = blockIdx.y * 32, n0 = blockIdx.x * 32;
    int tx = threadIdx.x & 31, ty = threadIdx.x >> 5;
#pragma unroll
    for (int i = 0; i < 4; ++i)
        tile[ty + i * 8][tx] = s[(size_t)(k0 + ty + i * 8) * N + (n0 + tx)];
    __syncthreads();
#pragma unroll
    for (int i = 0; i < 4; ++i)
        d[(size_t)(n0 + ty + i * 8) * K + (k0 + tx)] = f2bf(tile[tx][ty + i * 8]);
}

// ---------------- x init: src_emb fp32 -> xb bf16 ----------------
__global__ __launch_bounds__(256) void convert_x_kernel(
    const float* __restrict__ src, unsigned short* __restrict__ xb, int n4)
{
    int i = blockIdx.x * blockDim.x + threadIdx.x;
    int stride = gridDim.x * blockDim.x;
    for (; i < n4; i += stride) {
        float4 f = ((const float4*)src)[i];
        ushort4 u;
        u.x = f2bf(f.x); u.y = f2bf(f.y); u.z = f2bf(f.z); u.w = f2bf(f.w);
        ((ushort4*)xb)[i] = u;
    }
}

// ---------------- bf16 GEMM: C[M][N] = A[M][K] @ Bt[N][K]^T ----------------
// r3-proven structure, tile-parametrized: 4 waves (2x2), wave tile (BM/2)x(BN/2),
// BK=64, single-buffer LDS, 8-slot both-sides XOR swizzle slot^(row&7).
// Split-K via blockIdx.z writes partials at z*M*N.
template<int BM, int BN, bool OUTBF, bool DORELU>
__global__ __launch_bounds__(256) void gemm_kernel(
    const unsigned short* __restrict__ A,   // [M][K] bf16
    const unsigned short* __restrict__ Bt,  // [N][K] bf16
    float* __restrict__ Cf,                 // fp32 out (if !OUTBF)
    unsigned short* __restrict__ Cb,        // bf16 out (if OUTBF)
    const float* __restrict__ bias,         // [N] or null
    int M, int N, int K, int kLen)
{
    constexpr int BK = 64;
    constexpr int MT = BM / 32;    // 16-row frags per wave (M)
    constexpr int NT = BN / 32;    // 16-row frags per wave (N)
    __shared__ __align__(16) unsigned short As[BM * BK];
    __shared__ __align__(16) unsigned short Bs[BN * BK];
    int tid = threadIdx.x, lane = tid & 63, w = tid >> 6;
    int wr = w >> 1, wc = w & 1;

    // XCD-bijective swizzle over (x,y); nwg % 8 == 0 for all our grids
    int gx = gridDim.x;
    int nwg = gx * gridDim.y;
    int flat = blockIdx.x + gx * blockIdx.y;
    int qq = nwg >> 3;
    int swz = (flat & 7) * qq + (flat >> 3);
    int bx = swz % gx, by = swz / gx;
    int mBase = by * BM, nBase = bx * BN;
    int kStart = blockIdx.z * kLen;

    f32x4 acc[MT][NT];
#pragma unroll
    for (int i = 0; i < MT; ++i)
#pragma unroll
        for (int j = 0; j < NT; ++j) acc[i][j] = (f32x4){0.f, 0.f, 0.f, 0.f};

    for (int k0 = kStart; k0 < kStart + kLen; k0 += BK) {
        // stage A/B: row = i>>3, slot = i&7 (16B units), source col pre-XOR-swizzled
#pragma unroll
        for (int it = 0; it < BM * 8 / 256; ++it) {
            int i = it * 256 + tid;
            int row = i >> 3, slot = i & 7;
            int gcol = (slot ^ (row & 7)) * 8;
            const unsigned short* ga = A + (size_t)(mBase + row) * K + k0 + gcol;
            __builtin_amdgcn_global_load_lds(
                (const __attribute__((address_space(1))) void*)ga,
                (__attribute__((address_space(3))) void*)(As + i * 8), 16, 0, 0);
        }
#pragma unroll
        for (int it = 0; it < BN * 8 / 256; ++it) {
            int i = it * 256 + tid;
            int row = i >> 3, slot = i & 7;
            int gcol = (slot ^ (row & 7)) * 8;
            const unsigned short* gb = Bt + (size_t)(nBase + row) * K + k0 + gcol;
            __builtin_amdgcn_global_load_lds(
                (const __attribute__((address_space(1))) void*)gb,
                (__attribute__((address_space(3))) void*)(Bs + i * 8), 16, 0, 0);
        }
        __syncthreads();

        int rsel = lane & 15, g0 = lane >> 4;
        bf16x8 a[MT][2], b[NT][2];
#pragma unroll
        for (int m = 0; m < MT; ++m) {
            int row = wr * (BM / 2) + m * 16 + rsel;
#pragma unroll
            for (int ks = 0; ks < 2; ++ks) {
                int s = (g0 + ks * 4) ^ (row & 7);
                a[m][ks] = *(const bf16x8*)((const char*)As + row * 128 + s * 16);
            }
        }
#pragma unroll
        for (int n = 0; n < NT; ++n) {
            int row = wc * (BN / 2) + n * 16 + rsel;
#pragma unroll
            for (int ks = 0; ks < 2; ++ks) {
                int s = (g0 + ks * 4) ^ (row & 7);
                b[n][ks] = *(const bf16x8*)((const char*)Bs + row * 128 + s * 16);
            }
        }
#pragma unroll
        for (int m = 0; m < MT; ++m)
#pragma unroll
            for (int n = 0; n < NT; ++n)
#pragma unroll
                for (int ks = 0; ks < 2; ++ks)
                    acc[m][n] = __builtin_amdgcn_mfma_f32_16x16x32_bf16(a[m][ks], b[n][ks], acc[m][n], 0, 0, 0);
        __syncthreads();
    }

    // epilogue: C/D layout col=lane&15, row=(lane>>4)*4+j  [m89-verified]
    size_t zoff = (size_t)blockIdx.z * M * N;
    int rbase = (lane >> 4) * 4;
    int cloc = lane & 15;
#pragma unroll
    for (int m = 0; m < MT; ++m) {
#pragma unroll
        for (int n = 0; n < NT; ++n) {
            int col = nBase + wc * (BN / 2) + n * 16 + cloc;
            float bv = bias ? bias[col] : 0.0f;
#pragma unroll
            for (int j = 0; j < 4; ++j) {
                int row = mBase + wr * (BM / 2) + m * 16 + rbase + j;
                float val = acc[m][n][j] + bv;
                if (DORELU) val = fmaxf(val, 0.0f);
                if (OUTBF) Cb[zoff + (size_t)row * N + col] = f2bf(val);
                else       Cf[zoff + (size_t)row * N + col] = val;
            }
        }
    }
}

// ---------------- sparse relational attention (r4 structure) ----------------
__global__ __launch_bounds__(256) void attn_kernel(
    const unsigned short* __restrict__ qkv,
    const int* __restrict__ par, const int* __restrict__ bro,
    const float* __restrict__ relq, const float* __restrict__ relk,
    const float* __restrict__ relv, unsigned short* __restrict__ cb)
{
    int f = blockIdx.x;
    int xcd = f & 7;
    int j = f >> 3;                 // 0..255
    int b = xcd + 8 * (j & 1);
    int rem = j >> 1;               // 0..127
    int h = rem >> 4;               // 0..7
    int n0 = (rem & 15) * 32;
    int w = threadIdx.x >> 6;
    int lane = threadIdx.x & 63;
    int nw = n0 + w * 8;

    float rq[RR], rk[RR], rv[RR];
#pragma unroll
    for (int r = 0; r < RR; ++r) {
        rq[r] = relq[(h * RR + r) * DKK + lane];
        rk[r] = relk[(h * RR + r) * DKK + lane];
        rv[r] = relv[(h * RR + r) * DKK + lane];
    }
    const int* edges = (h < PAR_HEADS) ? par : bro;
    int e_all = edges[(b * RR + (lane & 7)) * NN + nw + (lane >> 3)];

    const unsigned short* qrow = qkv + (size_t)b * NN * 1536 + h * DKK;

#pragma unroll
    for (int nl = 0; nl < 8; ++nl) {
        int n = nw + nl;
        float qd = bf2f(qrow[(size_t)n * 1536 + lane]);
        float t[RR];
        int e[RR];
#pragma unroll
        for (int r = 0; r < RR; ++r) {
            int er = __builtin_amdgcn_readlane(e_all, nl * 8 + r);   // SGPR base
            e[r] = er;
            float kd = bf2f(qkv[(size_t)(b * NN + er) * 1536 + DMM + h * DKK + lane]);
            t[r] = kd * (qd + rq[r]) + qd * rk[r];
        }
        {
            bool hb = lane & 4;
#pragma unroll
            for (int rr = 0; rr < 4; ++rr) {
                float send = hb ? t[rr] : t[rr + 4];
                float keep = hb ? t[rr + 4] : t[rr];
                t[rr] = keep + __shfl_xor(send, 4, 64);
            }
        }
        {
            bool hb = lane & 2;
#pragma unroll
            for (int rr = 0; rr < 2; ++rr) {
                float send = hb ? t[rr] : t[rr + 2];
                float keep = hb ? t[rr + 2] : t[rr];
                t[rr] = keep + __shfl_xor(send, 2, 64);
            }
        }
        {
            bool hb = lane & 1;
            float send = hb ? t[0] : t[1];
            float keep = hb ? t[1] : t[0];
            t[0] = keep + __shfl_xor(send, 1, 64);
        }
        float s = t[0];
        s += __shfl_xor(s, 8, 64);
        s += __shfl_xor(s, 16, 64);
        s += __shfl_xor(s, 32, 64);
        s *= 0.125f;
        float mx = s;
        mx = fmaxf(mx, __shfl_xor(mx, 1, 64));
        mx = fmaxf(mx, __shfl_xor(mx, 2, 64));
        mx = fmaxf(mx, __shfl_xor(mx, 4, 64));
        float ee = __expf(s - mx);
        float den = ee;
        den += __shfl_xor(den, 1, 64);
        den += __shfl_xor(den, 2, 64);
        den += __shfl_xor(den, 4, 64);
        float a = ee / den;
        float od = 0.f;
#pragma unroll
        for (int r = 0; r < RR; ++r) {
            float ar = __shfl(a, (lane & 56) | r, 64);
            float vd = bf2f(qkv[(size_t)(b * NN + e[r]) * 1536 + 2 * DMM + h * DKK + lane]);
            od = fmaf(ar, vd + rv[r], od);
        }
        cb[(size_t)(b * NN + n) * DMM + h * DKK + lane] = f2bf(od);
    }
}

// ---------------- residual(+partials+bias) + LayerNorm, bf16 residual stream ----
// reads xbin (bf16) + optional fp32 partials/bias; writes xbout (bf16) and/or
// xfout (fp32, final layer -> d_out). One wave per row; lane = 8 contiguous cols.
__global__ __launch_bounds__(256) void ln_kernel(
    const unsigned short* __restrict__ xbin, const float* __restrict__ add0,
    const float* __restrict__ add1, const float* __restrict__ bias,
    unsigned short* __restrict__ xbout, float* __restrict__ xfout,
    const float* __restrict__ g, const float* __restrict__ bb)
{
    int row = blockIdx.x * 4 + (threadIdx.x >> 6);
    int lane = threadIdx.x & 63;
    int c0 = lane * 8;
    float vals[8];
    {
        u16x8 u = *(const u16x8*)(xbin + (size_t)row * DMM + c0);
#pragma unroll
        for (int j = 0; j < 8; ++j) vals[j] = bf2f(u[j]);
    }
    if (add0) {
        const float* ar = add0 + (size_t)row * DMM + c0;
        float4 v0 = *(const float4*)ar, v1 = *(const float4*)(ar + 4);
        vals[0] += v0.x; vals[1] += v0.y; vals[2] += v0.z; vals[3] += v0.w;
        vals[4] += v1.x; vals[5] += v1.y; vals[6] += v1.z; vals[7] += v1.w;
    }
    if (add1) {
        const float* ar = add1 + (size_t)row * DMM + c0;
        float4 v0 = *(const float4*)ar, v1 = *(const float4*)(ar + 4);
        vals[0] += v0.x; vals[1] += v0.y; vals[2] += v0.z; vals[3] += v0.w;
        vals[4] += v1.x; vals[5] += v1.y; vals[6] += v1.z; vals[7] += v1.w;
    }
    if (bias) {
        float4 v0 = *(const float4*)(bias + c0), v1 = *(const float4*)(bias + c0 + 4);
        vals[0] += v0.x; vals[1] += v0.y; vals[2] += v0.z; vals[3] += v0.w;
        vals[4] += v1.x; vals[5] += v1.y; vals[6] += v1.z; vals[7] += v1.w;
    }
    float s = 0.f;
#pragma unroll
    for (int j = 0; j < 8; ++j) s += vals[j];
#pragma unroll
    for (int off = 32; off > 0; off >>= 1) s += __shfl_xor(s, off, 64);
    float mean = s * (1.0f / DMM);
    float s2 = 0.f;
#pragma unroll
    for (int j = 0; j < 8; ++j) { float d = vals[j] - mean; s2 += d * d; }
#pragma unroll
    for (int off = 32; off > 0; off >>= 1) s2 += __shfl_xor(s2, off, 64);
    float inv = rsqrtf(s2 * (1.0f / DMM) + EPSV);

    float4 gv0 = *(const float4*)(g + c0), gv1 = *(const float4*)(g + c0 + 4);
    float4 bv0 = *(const float4*)(bb + c0), bv1 = *(const float4*)(bb + c0 + 4);
    float y[8];
    y[0] = (vals[0] - mean) * inv * gv0.x + bv0.x;
    y[1] = (vals[1] - mean) * inv * gv0.y + bv0.y;
    y[2] = (vals[2] - mean) * inv * gv0.z + bv0.z;
    y[3] = (vals[3] - mean) * inv * gv0.w + bv0.w;
    y[4] = (vals[4] - mean) * inv * gv1.x + bv1.x;
    y[5] = (vals[5] - mean) * inv * gv1.y + bv1.y;
    y[6] = (vals[6] - mean) * inv * gv1.z + bv1.z;
    y[7] = (vals[7] - mean) * inv * gv1.w + bv1.w;

    if (xbout) {
        u16x8 u;
#pragma unroll
        for (int j = 0; j < 8; ++j) u[j] = f2bf(y[j]);
        *(u16x8*)(xbout + (size_t)row * DMM + c0) = u;
    }
    if (xfout) {
        float* xo = xfout + (size_t)row * DMM + c0;
        *(float4*)xo = make_float4(y[0], y[1], y[2], y[3]);
        *(float4*)(xo + 4) = make_float4(y[4], y[5], y[6], y[7]);
    }
}

extern "C" void kernel_launch(void* const* d_in, const int* in_sizes, int n_in,
                              void* d_out, int out_size, void* d_ws, size_t ws_size,
                              hipStream_t stream)
{
    const float* src_emb = (const float*)d_in[0];
    const int*   par     = (const int*)d_in[1];
    const int*   bro     = (const int*)d_in[2];
    const float* rel_q   = (const float*)d_in[3];
    const float* rel_k   = (const float*)d_in[4];
    const float* rel_v   = (const float*)d_in[5];
    const float* Wq      = (const float*)d_in[6];
    const float* Wk      = (const float*)d_in[7];
    const float* Wv      = (const float*)d_in[8];
    const float* Wo      = (const float*)d_in[9];
    const float* ln1_g   = (const float*)d_in[10];
    const float* ln1_b   = (const float*)d_in[11];
    const float* W1      = (const float*)d_in[12];
    const float* b1      = (const float*)d_in[13];
    const float* W2      = (const float*)d_in[14];
    const float* b2      = (const float*)d_in[15];
    const float* ln2_g   = (const float*)d_in[16];
    const float* ln2_b   = (const float*)d_in[17];
    const float* normf_g = (const float*)d_in[18];
    const float* normf_b = (const float*)d_in[19];

    const size_t MB = 1024 * 1024;
    const int M = BB * NN;  // 8192
    char* ws = (char*)d_ws;
    float*          p    = (float*)(ws + 0 * MB);
    unsigned short* qkvb = (unsigned short*)(ws + 0 * MB);    // overlaps p (disjoint lifetime)
    unsigned short* h1   = (unsigned short*)(ws + 32 * MB);
    unsigned short* xb   = (unsigned short*)(ws + 64 * MB);
    unsigned short* cbuf = (unsigned short*)(ws + 72 * MB);
    unsigned short* wqkvT = (unsigned short*)(ws + 80 * MB);
    unsigned short* woT  = wqkvT + (size_t)LL * 1536 * DMM;
    unsigned short* w1T  = woT + (size_t)LL * DMM * DMM;
    unsigned short* w2T  = w1T + (size_t)LL * DMM * DFFV;
    float* p0 = p;
    float* p1 = p + (size_t)M * DMM;
    float* x = (float*)d_out;

    transpose_qkvo_kernel<<<dim3(16, 16, LL * 4), 256, 0, stream>>>(
        Wq, Wk, Wv, Wo, wqkvT, woT);
    transpose_w_kernel<<<dim3(DFFV / 32, DMM / 32, LL), 256, 0, stream>>>(
        W1, w1T, DMM, DFFV, (size_t)DMM * DFFV);
    transpose_w_kernel<<<dim3(DMM / 32, DFFV / 32, LL), 256, 0, stream>>>(
        W2, w2T, DFFV, DMM, (size_t)DMM * DFFV);

    convert_x_kernel<<<2048, 256, 0, stream>>>(src_emb, xb, M * DMM / 4);

    for (int l = 0; l < LL; ++l) {
        const unsigned short* wqkv_l = wqkvT + (size_t)l * 1536 * DMM;
        const unsigned short* wo_l = woT + (size_t)l * DMM * DMM;
        const unsigned short* w1_l = w1T + (size_t)l * DMM * DFFV;
        const unsigned short* w2_l = w2T + (size_t)l * DFFV * DMM;

        // fused QKV: 128x128 tile, grid (12,64)=768 = 3 blocks/CU
        gemm_kernel<128, 128, true, false><<<dim3(1536 / 128, M / 128, 1), 256, 0, stream>>>(
            xb, wqkv_l, nullptr, qkvb, nullptr, M, 1536, DMM, DMM);

        attn_kernel<<<2048, 256, 0, stream>>>(qkvb, par, bro, rel_q, rel_k, rel_v, cbuf);

        // Wo: 128x64 split-K=2, grid (8,64,2)=1024; partials summed in ln1
        gemm_kernel<128, 64, false, false><<<dim3(512 / 64, M / 128, 2), 256, 0, stream>>>(
            cbuf, wo_l, p, nullptr, nullptr, M, DMM, DMM, DMM / 2);
        ln_kernel<<<M / 4, 256, 0, stream>>>(xb, p0, p1, nullptr, xb, nullptr,
                                             ln1_g + l * DMM, ln1_b + l * DMM);

        // W1: 128x128 tile, bias+relu, bf16 out; grid (16,64)=1024 = 4 blocks/CU
        gemm_kernel<128, 128, true, true><<<dim3(DFFV / 128, M / 128, 1), 256, 0, stream>>>(
            xb, w1_l, nullptr, h1, b1 + l * DFFV, M, DFFV, DMM, DMM);
        // W2: 128x64 split-K=2 (K=1024 each); b2 added in ln2
        gemm_kernel<128, 64, false, false><<<dim3(512 / 64, M / 128, 2), 256, 0, stream>>>(
            h1, w2_l, p, nullptr, nullptr, M, DMM, DFFV, DFFV / 2);
        ln_kernel<<<M / 4, 256, 0, stream>>>(xb, p0, p1, b2 + l * DMM, xb, nullptr,
                                             ln2_g + l * DMM, ln2_b + l * DMM);
    }

    // final norm: bf16 residual in -> fp32 d_out
    ln_kernel<<<M / 4, 256, 0, stream>>>(xb, nullptr, nullptr, nullptr, nullptr, x,
                                         normf_g, normf_b);
}

// Round 15
// 437.837 us; speedup vs baseline: 1.0734x; 1.0004x over previous
//
#include <hip/hip_runtime.h>
#include <hip/hip_bf16.h>

// FastASTEncoder round 11 (resubmit x4 — acquisition timeouts): best-of-measured.
// GEMM: uniform 128x64/BK=64 single-buffer (r7-measured <=40us; 128x128 measured
// 47.4us in r10 -> reverted). bf16 residual stream kept (r10's -20us). attn = r4.
//
// Workspace (~92 MiB):
//   [0,32M)   p0/p1 fp32 partials [2][8192][512]  (overlaps qkvb bf16 [8192][1536])
//   [32,64M)  h1   bf16 [8192][2048]
//   [64,72M)  xb   bf16 [8192][512]  (residual stream, bf16)
//   [72,80M)  cbuf bf16 [8192][512]
//   [80M+)    transposed bf16 weights

#define BB 16
#define NN 512
#define DMM 512
#define HH 8
#define DKK 64
#define RR 8
#define LL 2
#define DFFV 2048
#define PAR_HEADS 4
#define EPSV 1e-5f

typedef __bf16 bf16x8 __attribute__((ext_vector_type(8)));
typedef float f32x4 __attribute__((ext_vector_type(4)));
typedef unsigned short u16x8 __attribute__((ext_vector_type(8)));

__device__ __forceinline__ unsigned short f2bf(float f) {
    unsigned u = __float_as_uint(f);
    u += 0x7fff + ((u >> 16) & 1);   // RNE
    return (unsigned short)(u >> 16);
}
__device__ __forceinline__ float bf2f(unsigned short u) {
    return __uint_as_float(((unsigned)u) << 16);
}

// ---------------- fused transpose for the four [512][512] weight sets ----------------
__global__ __launch_bounds__(256) void transpose_qkvo_kernel(
    const float* __restrict__ Wq, const float* __restrict__ Wk,
    const float* __restrict__ Wv, const float* __restrict__ Wo,
    unsigned short* __restrict__ wqkvT, unsigned short* __restrict__ woT)
{
    __shared__ float tile[32][33];
    int layer = blockIdx.z >> 2, which = blockIdx.z & 3;
    const float* s = (which == 0 ? Wq : which == 1 ? Wk : which == 2 ? Wv : Wo)
                     + (size_t)layer * DMM * DMM;
    unsigned short* d = (which < 3)
        ? wqkvT + (size_t)layer * 1536 * DMM + (size_t)which * DMM * DMM
        : woT + (size_t)layer * DMM * DMM;
    int k0 = blockIdx.y * 32, n0 = blockIdx.x * 32;
    int tx = threadIdx.x & 31, ty = threadIdx.x >> 5;
#pragma unroll
    for (int i = 0; i < 4; ++i)
        tile[ty + i * 8][tx] = s[(size_t)(k0 + ty + i * 8) * DMM + (n0 + tx)];
    __syncthreads();
#pragma unroll
    for (int i = 0; i < 4; ++i)
        d[(size_t)(n0 + ty + i * 8) * DMM + (k0 + tx)] = f2bf(tile[tx][ty + i * 8]);
}

// generic transpose [z][K][N] fp32 -> bf16 [N][K] (for W1, W2)
__global__ __launch_bounds__(256) void transpose_w_kernel(
    const float* __restrict__ src, unsigned short* __restrict__ dst,
    int K, int N, size_t zStride)
{
    __shared__ float tile[32][33];
    const float* s = src + (size_t)blockIdx.z * K * N;
    unsigned short* d = dst + (size_t)blockIdx.z * zStride;
    int k0 = blockIdx.y * 32, n0 = blockIdx.x * 32;
    int tx = threadIdx.x & 31, ty = threadIdx.x >> 5;
#pragma unroll
    for (int i = 0; i < 4; ++i)
        tile[ty + i * 8][tx] = s[(size_t)(k0 + ty + i * 8) * N + (n0 + tx)];
    __syncthreads();
#pragma unroll
    for (int i = 0; i < 4; ++i)
        d[(size_t)(n0 + ty + i * 8) * K + (k0 + tx)] = f2bf(tile[tx][ty + i * 8]);
}

// ---------------- x init: src_emb fp32 -> xb bf16 ----------------
__global__ __launch_bounds__(256) void convert_x_kernel(
    const float* __restrict__ src, unsigned short* __restrict__ xb, int n4)
{
    int i = blockIdx.x * blockDim.x + threadIdx.x;
    int stride = gridDim.x * blockDim.x;
    for (; i < n4; i += stride) {
        float4 f = ((const float4*)src)[i];
        ushort4 u;
        u.x = f2bf(f.x); u.y = f2bf(f.y); u.z = f2bf(f.z); u.w = f2bf(f.w);
        ((ushort4*)xb)[i] = u;
    }
}

// ---------------- bf16 GEMM: C[M][N] = A[M][K] @ Bt[N][K]^T ----------------
// r3/r7-proven structure: 128x64 tile, BK=64, 4 waves (2x2), wave tile 64x32,
// 16 MFMA/wave/K-step, single-buffer 24KB LDS (6 blocks/CU), 8-slot both-sides
// XOR swizzle slot^(row&7) (0 conflicts measured). Split-K via blockIdx.z.
template<bool OUTBF, bool DORELU>
__global__ __launch_bounds__(256) void gemm_kernel(
    const unsigned short* __restrict__ A,   // [M][K] bf16
    const unsigned short* __restrict__ Bt,  // [N][K] bf16
    float* __restrict__ Cf,                 // fp32 out (if !OUTBF)
    unsigned short* __restrict__ Cb,        // bf16 out (if OUTBF)
    const float* __restrict__ bias,         // [N] or null
    int M, int N, int K, int kLen)
{
    constexpr int BM = 128, BN = 64, BK = 64;
    __shared__ __align__(16) unsigned short As[BM * BK];
    __shared__ __align__(16) unsigned short Bs[BN * BK];
    int tid = threadIdx.x, lane = tid & 63, w = tid >> 6;
    int wr = w >> 1, wc = w & 1;

    // XCD-bijective swizzle over (x,y); nwg % 8 == 0 for all our grids
    int gx = gridDim.x;
    int nwg = gx * gridDim.y;
    int flat = blockIdx.x + gx * blockIdx.y;
    int qq = nwg >> 3;
    int swz = (flat & 7) * qq + (flat >> 3);
    int bx = swz % gx, by = swz / gx;
    int mBase = by * BM, nBase = bx * BN;
    int kStart = blockIdx.z * kLen;

    f32x4 acc[4][2];
#pragma unroll
    for (int i = 0; i < 4; ++i)
#pragma unroll
        for (int j = 0; j < 2; ++j) acc[i][j] = (f32x4){0.f, 0.f, 0.f, 0.f};

    for (int k0 = kStart; k0 < kStart + kLen; k0 += BK) {
        // stage A: 1024 16B units (row=i>>3, slot=i&7), source column pre-XOR-swizzled
#pragma unroll
        for (int it = 0; it < 4; ++it) {
            int i = it * 256 + tid;
            int row = i >> 3, slot = i & 7;
            int gcol = (slot ^ (row & 7)) * 8;
            const unsigned short* ga = A + (size_t)(mBase + row) * K + k0 + gcol;
            __builtin_amdgcn_global_load_lds(
                (const __attribute__((address_space(1))) void*)ga,
                (__attribute__((address_space(3))) void*)(As + i * 8), 16, 0, 0);
        }
#pragma unroll
        for (int it = 0; it < 2; ++it) {
            int i = it * 256 + tid;
            int row = i >> 3, slot = i & 7;
            int gcol = (slot ^ (row & 7)) * 8;
            const unsigned short* gb = Bt + (size_t)(nBase + row) * K + k0 + gcol;
            __builtin_amdgcn_global_load_lds(
                (const __attribute__((address_space(1))) void*)gb,
                (__attribute__((address_space(3))) void*)(Bs + i * 8), 16, 0, 0);
        }
        __syncthreads();

        int rsel = lane & 15, g0 = lane >> 4;
        bf16x8 a[4][2], b[2][2];
#pragma unroll
        for (int m = 0; m < 4; ++m) {
            int row = wr * 64 + m * 16 + rsel;
#pragma unroll
            for (int ks = 0; ks < 2; ++ks) {
                int s = (g0 + ks * 4) ^ (row & 7);
                a[m][ks] = *(const bf16x8*)((const char*)As + row * 128 + s * 16);
            }
        }
#pragma unroll
        for (int n = 0; n < 2; ++n) {
            int row = wc * 32 + n * 16 + rsel;
#pragma unroll
            for (int ks = 0; ks < 2; ++ks) {
                int s = (g0 + ks * 4) ^ (row & 7);
                b[n][ks] = *(const bf16x8*)((const char*)Bs + row * 128 + s * 16);
            }
        }
#pragma unroll
        for (int m = 0; m < 4; ++m)
#pragma unroll
            for (int n = 0; n < 2; ++n)
#pragma unroll
                for (int ks = 0; ks < 2; ++ks)
                    acc[m][n] = __builtin_amdgcn_mfma_f32_16x16x32_bf16(a[m][ks], b[n][ks], acc[m][n], 0, 0, 0);
        __syncthreads();
    }

    // epilogue: C/D layout col=lane&15, row=(lane>>4)*4+j  [m89-verified]
    size_t zoff = (size_t)blockIdx.z * M * N;
    int rbase = (lane >> 4) * 4;
    int cloc = lane & 15;
#pragma unroll
    for (int m = 0; m < 4; ++m) {
#pragma unroll
        for (int n = 0; n < 2; ++n) {
            int col = nBase + wc * 32 + n * 16 + cloc;
            float bv = bias ? bias[col] : 0.0f;
#pragma unroll
            for (int j = 0; j < 4; ++j) {
                int row = mBase + wr * 64 + m * 16 + rbase + j;
                float val = acc[m][n][j] + bv;
                if (DORELU) val = fmaxf(val, 0.0f);
                if (OUTBF) Cb[zoff + (size_t)row * N + col] = f2bf(val);
                else       Cf[zoff + (size_t)row * N + col] = val;
            }
        }
    }
}

// ---------------- sparse relational attention (r4 structure) ----------------
__global__ __launch_bounds__(256) void attn_kernel(
    const unsigned short* __restrict__ qkv,
    const int* __restrict__ par, const int* __restrict__ bro,
    const float* __restrict__ relq, const float* __restrict__ relk,
    const float* __restrict__ relv, unsigned short* __restrict__ cb)
{
    int f = blockIdx.x;
    int xcd = f & 7;
    int j = f >> 3;                 // 0..255
    int b = xcd + 8 * (j & 1);
    int rem = j >> 1;               // 0..127
    int h = rem >> 4;               // 0..7
    int n0 = (rem & 15) * 32;
    int w = threadIdx.x >> 6;
    int lane = threadIdx.x & 63;
    int nw = n0 + w * 8;

    float rq[RR], rk[RR], rv[RR];
#pragma unroll
    for (int r = 0; r < RR; ++r) {
        rq[r] = relq[(h * RR + r) * DKK + lane];
        rk[r] = relk[(h * RR + r) * DKK + lane];
        rv[r] = relv[(h * RR + r) * DKK + lane];
    }
    const int* edges = (h < PAR_HEADS) ? par : bro;
    int e_all = edges[(b * RR + (lane & 7)) * NN + nw + (lane >> 3)];

    const unsigned short* qrow = qkv + (size_t)b * NN * 1536 + h * DKK;

#pragma unroll
    for (int nl = 0; nl < 8; ++nl) {
        int n = nw + nl;
        float qd = bf2f(qrow[(size_t)n * 1536 + lane]);
        float t[RR];
        int e[RR];
#pragma unroll
        for (int r = 0; r < RR; ++r) {
            int er = __builtin_amdgcn_readlane(e_all, nl * 8 + r);   // SGPR base
            e[r] = er;
            float kd = bf2f(qkv[(size_t)(b * NN + er) * 1536 + DMM + h * DKK + lane]);
            t[r] = kd * (qd + rq[r]) + qd * rk[r];
        }
        {
            bool hb = lane & 4;
#pragma unroll
            for (int rr = 0; rr < 4; ++rr) {
                float send = hb ? t[rr] : t[rr + 4];
                float keep = hb ? t[rr + 4] : t[rr];
                t[rr] = keep + __shfl_xor(send, 4, 64);
            }
        }
        {
            bool hb = lane & 2;
#pragma unroll
            for (int rr = 0; rr < 2; ++rr) {
                float send = hb ? t[rr] : t[rr + 2];
                float keep = hb ? t[rr + 2] : t[rr];
                t[rr] = keep + __shfl_xor(send, 2, 64);
            }
        }
        {
            bool hb = lane & 1;
            float send = hb ? t[0] : t[1];
            float keep = hb ? t[1] : t[0];
            t[0] = keep + __shfl_xor(send, 1, 64);
        }
        float s = t[0];
        s += __shfl_xor(s, 8, 64);
        s += __shfl_xor(s, 16, 64);
        s += __shfl_xor(s, 32, 64);
        s *= 0.125f;
        float mx = s;
        mx = fmaxf(mx, __shfl_xor(mx, 1, 64));
        mx = fmaxf(mx, __shfl_xor(mx, 2, 64));
        mx = fmaxf(mx, __shfl_xor(mx, 4, 64));
        float ee = __expf(s - mx);
        float den = ee;
        den += __shfl_xor(den, 1, 64);
        den += __shfl_xor(den, 2, 64);
        den += __shfl_xor(den, 4, 64);
        float a = ee / den;
        float od = 0.f;
#pragma unroll
        for (int r = 0; r < RR; ++r) {
            float ar = __shfl(a, (lane & 56) | r, 64);
            float vd = bf2f(qkv[(size_t)(b * NN + e[r]) * 1536 + 2 * DMM + h * DKK + lane]);
            od = fmaf(ar, vd + rv[r], od);
        }
        cb[(size_t)(b * NN + n) * DMM + h * DKK + lane] = f2bf(od);
    }
}

// ---------------- residual(+partials+bias) + LayerNorm, bf16 residual stream ----
__global__ __launch_bounds__(256) void ln_kernel(
    const unsigned short* __restrict__ xbin, const float* __restrict__ add0,
    const float* __restrict__ add1, const float* __restrict__ bias,
    unsigned short* __restrict__ xbout, float* __restrict__ xfout,
    const float* __restrict__ g, const float* __restrict__ bb)
{
    int row = blockIdx.x * 4 + (threadIdx.x >> 6);
    int lane = threadIdx.x & 63;
    int c0 = lane * 8;
    float vals[8];
    {
        u16x8 u = *(const u16x8*)(xbin + (size_t)row * DMM + c0);
#pragma unroll
        for (int j = 0; j < 8; ++j) vals[j] = bf2f(u[j]);
    }
    if (add0) {
        const float* ar = add0 + (size_t)row * DMM + c0;
        float4 v0 = *(const float4*)ar, v1 = *(const float4*)(ar + 4);
        vals[0] += v0.x; vals[1] += v0.y; vals[2] += v0.z; vals[3] += v0.w;
        vals[4] += v1.x; vals[5] += v1.y; vals[6] += v1.z; vals[7] += v1.w;
    }
    if (add1) {
        const float* ar = add1 + (size_t)row * DMM + c0;
        float4 v0 = *(const float4*)ar, v1 = *(const float4*)(ar + 4);
        vals[0] += v0.x; vals[1] += v0.y; vals[2] += v0.z; vals[3] += v0.w;
        vals[4] += v1.x; vals[5] += v1.y; vals[6] += v1.z; vals[7] += v1.w;
    }
    if (bias) {
        float4 v0 = *(const float4*)(bias + c0), v1 = *(const float4*)(bias + c0 + 4);
        vals[0] += v0.x; vals[1] += v0.y; vals[2] += v0.z; vals[3] += v0.w;
        vals[4] += v1.x; vals[5] += v1.y; vals[6] += v1.z; vals[7] += v1.w;
    }
    float s = 0.f;
#pragma unroll
    for (int j = 0; j < 8; ++j) s += vals[j];
#pragma unroll
    for (int off = 32; off > 0; off >>= 1) s += __shfl_xor(s, off, 64);
    float mean = s * (1.0f / DMM);
    float s2 = 0.f;
#pragma unroll
    for (int j = 0; j < 8; ++j) { float d = vals[j] - mean; s2 += d * d; }
#pragma unroll
    for (int off = 32; off > 0; off >>= 1) s2 += __shfl_xor(s2, off, 64);
    float inv = rsqrtf(s2 * (1.0f / DMM) + EPSV);

    float4 gv0 = *(const float4*)(g + c0), gv1 = *(const float4*)(g + c0 + 4);
    float4 bv0 = *(const float4*)(bb + c0), bv1 = *(const float4*)(bb + c0 + 4);
    float y[8];
    y[0] = (vals[0] - mean) * inv * gv0.x + bv0.x;
    y[1] = (vals[1] - mean) * inv * gv0.y + bv0.y;
    y[2] = (vals[2] - mean) * inv * gv0.z + bv0.z;
    y[3] = (vals[3] - mean) * inv * gv0.w + bv0.w;
    y[4] = (vals[4] - mean) * inv * gv1.x + bv1.x;
    y[5] = (vals[5] - mean) * inv * gv1.y + bv1.y;
    y[6] = (vals[6] - mean) * inv * gv1.z + bv1.z;
    y[7] = (vals[7] - mean) * inv * gv1.w + bv1.w;

    if (xbout) {
        u16x8 u;
#pragma unroll
        for (int j = 0; j < 8; ++j) u[j] = f2bf(y[j]);
        *(u16x8*)(xbout + (size_t)row * DMM + c0) = u;
    }
    if (xfout) {
        float* xo = xfout + (size_t)row * DMM + c0;
        *(float4*)xo = make_float4(y[0], y[1], y[2], y[3]);
        *(float4*)(xo + 4) = make_float4(y[4], y[5], y[6], y[7]);
    }
}

extern "C" void kernel_launch(void* const* d_in, const int* in_sizes, int n_in,
                              void* d_out, int out_size, void* d_ws, size_t ws_size,
                              hipStream_t stream)
{
    const float* src_emb = (const float*)d_in[0];
    const int*   par     = (const int*)d_in[1];
    const int*   bro     = (const int*)d_in[2];
    const float* rel_q   = (const float*)d_in[3];
    const float* rel_k   = (const float*)d_in[4];
    const float* rel_v   = (const float*)d_in[5];
    const float* Wq      = (const float*)d_in[6];
    const float* Wk      = (const float*)d_in[7];
    const float* Wv      = (const float*)d_in[8];
    const float* Wo      = (const float*)d_in[9];
    const float* ln1_g   = (const float*)d_in[10];
    const float* ln1_b   = (const float*)d_in[11];
    const float* W1      = (const float*)d_in[12];
    const float* b1      = (const float*)d_in[13];
    const float* W2      = (const float*)d_in[14];
    const float* b2      = (const float*)d_in[15];
    const float* ln2_g   = (const float*)d_in[16];
    const float* ln2_b   = (const float*)d_in[17];
    const float* normf_g = (const float*)d_in[18];
    const float* normf_b = (const float*)d_in[19];

    const size_t MB = 1024 * 1024;
    const int M = BB * NN;  // 8192
    char* ws = (char*)d_ws;
    float*          p    = (float*)(ws + 0 * MB);
    unsigned short* qkvb = (unsigned short*)(ws + 0 * MB);    // overlaps p (disjoint lifetime)
    unsigned short* h1   = (unsigned short*)(ws + 32 * MB);
    unsigned short* xb   = (unsigned short*)(ws + 64 * MB);
    unsigned short* cbuf = (unsigned short*)(ws + 72 * MB);
    unsigned short* wqkvT = (unsigned short*)(ws + 80 * MB);
    unsigned short* woT  = wqkvT + (size_t)LL * 1536 * DMM;
    unsigned short* w1T  = woT + (size_t)LL * DMM * DMM;
    unsigned short* w2T  = w1T + (size_t)LL * DMM * DFFV;
    float* p0 = p;
    float* p1 = p + (size_t)M * DMM;
    float* x = (float*)d_out;

    transpose_qkvo_kernel<<<dim3(16, 16, LL * 4), 256, 0, stream>>>(
        Wq, Wk, Wv, Wo, wqkvT, woT);
    transpose_w_kernel<<<dim3(DFFV / 32, DMM / 32, LL), 256, 0, stream>>>(
        W1, w1T, DMM, DFFV, (size_t)DMM * DFFV);
    transpose_w_kernel<<<dim3(DMM / 32, DFFV / 32, LL), 256, 0, stream>>>(
        W2, w2T, DFFV, DMM, (size_t)DMM * DFFV);

    convert_x_kernel<<<2048, 256, 0, stream>>>(src_emb, xb, M * DMM / 4);

    for (int l = 0; l < LL; ++l) {
        const unsigned short* wqkv_l = wqkvT + (size_t)l * 1536 * DMM;
        const unsigned short* wo_l = woT + (size_t)l * DMM * DMM;
        const unsigned short* w1_l = w1T + (size_t)l * DMM * DFFV;
        const unsigned short* w2_l = w2T + (size_t)l * DFFV * DMM;

        // fused QKV: 128x64, grid (24,64)=1536 = 6 blocks/CU
        gemm_kernel<true, false><<<dim3(1536 / 64, M / 128, 1), 256, 0, stream>>>(
            xb, wqkv_l, nullptr, qkvb, nullptr, M, 1536, DMM, DMM);

        attn_kernel<<<2048, 256, 0, stream>>>(qkvb, par, bro, rel_q, rel_k, rel_v, cbuf);

        // Wo: 128x64 split-K=2, grid (8,64,2)=1024; partials summed in ln1
        gemm_kernel<false, false><<<dim3(512 / 64, M / 128, 2), 256, 0, stream>>>(
            cbuf, wo_l, p, nullptr, nullptr, M, DMM, DMM, DMM / 2);
        ln_kernel<<<M / 4, 256, 0, stream>>>(xb, p0, p1, nullptr, xb, nullptr,
                                             ln1_g + l * DMM, ln1_b + l * DMM);

        // W1: 128x64, bias+relu, bf16 out; grid (32,64)=2048 = 8 blocks/CU
        gemm_kernel<true, true><<<dim3(DFFV / 64, M / 128, 1), 256, 0, stream>>>(
            xb, w1_l, nullptr, h1, b1 + l * DFFV, M, DFFV, DMM, DMM);
        // W2: 128x64 split-K=2 (K=1024 each); b2 added in ln2
        gemm_kernel<false, false><<<dim3(512 / 64, M / 128, 2), 256, 0, stream>>>(
            h1, w2_l, p, nullptr, nullptr, M, DMM, DFFV, DFFV / 2);
        ln_kernel<<<M / 4, 256, 0, stream>>>(xb, p0, p1, b2 + l * DMM, xb, nullptr,
                                             ln2_g + l * DMM, ln2_b + l * DMM);
    }

    // final norm: bf16 residual in -> fp32 d_out
    ln_kernel<<<M / 4, 256, 0, stream>>>(xb, nullptr, nullptr, nullptr, nullptr, x,
                                         normf_g, normf_b);
}